// Round 5
// baseline (640.211 us; speedup 1.0000x reference)
//
#include <hip/hip_runtime.h>
#include <hip/hip_bf16.h>

#define DEVINL __device__ __forceinline__

typedef short short8 __attribute__((ext_vector_type(8)));
typedef float f32x4 __attribute__((ext_vector_type(4)));

namespace {
constexpr int NB = 2;
constexpr int NN = 4096;
constexpr int KK = 32;
constexpr int NP = NN * KK;      // 131072 points per batch
constexpr float R2 = 0.01f;
constexpr float GEPS = 1e-5f;
}

// split fp32 v into bf16 hi + bf16 lo (truncation; v - hi is exact)
DEVINL ushort2 splitbf(float v) {
    unsigned int b = __float_as_uint(v);
    unsigned int hb = b & 0xffff0000u;
    float r = v - __uint_as_float(hb);
    unsigned int lb = __float_as_uint(r);
    ushort2 res;
    res.x = (unsigned short)(hb >> 16);
    res.y = (unsigned short)(lb >> 16);
    return res;
}

DEVINL float angle3(float ax, float ay, float az, float bx, float by, float bz) {
    float crx = ay * bz - az * by;
    float cry = az * bx - ax * bz;
    float crz = ax * by - ay * bx;
    float sq = crx * crx + cry * cry + crz * crz;
    float yv = sq > 0.f ? sqrtf(sq) : 0.f;
    float xv = ax * bx + ay * by + az * bz;
    if (yv == 0.f && xv == 0.f) return 0.f;
    return atan2f(yv, xv);
}

template <int NV>
DEVINL void blockReduceAdd(float* vals, float* __restrict__ gout) {
    #pragma unroll
    for (int m = 1; m < 64; m <<= 1) {
        #pragma unroll
        for (int q = 0; q < NV; ++q) vals[q] += __shfl_xor(vals[q], m, 64);
    }
    __shared__ float red[4][NV];
    int lane = threadIdx.x & 63, w = threadIdx.x >> 6;
    if (lane == 0) {
        #pragma unroll
        for (int q = 0; q < NV; ++q) red[w][q] = vals[q];
    }
    __syncthreads();
    if ((int)threadIdx.x < NV) {
        float v = red[0][threadIdx.x] + red[1][threadIdx.x] +
                  red[2][threadIdx.x] + red[3][threadIdx.x];
        atomicAdd(&gout[threadIdx.x], v);
    }
}

// w0t[c*64+o] = w0[o*13+c]; a1/a2: split-bf16 weights in MFMA A-frag layout.
// A-frag entry x = mt*128 + ks*64 + lane; element e: W[mt*16+(lane&15)][ks*32+(lane>>4)*8+e]
__global__ void k_prep(const float* __restrict__ w0, const float* __restrict__ w1,
                       const float* __restrict__ w2, float* __restrict__ w0t,
                       short* __restrict__ a1hi, short* __restrict__ a1lo,
                       short* __restrict__ a2hi, short* __restrict__ a2lo) {
    int t = threadIdx.x;
    for (int x = t; x < 64 * 13; x += 256) { int o = x / 13, c = x % 13; w0t[c * 64 + o] = w0[x]; }
    for (int x = t; x < 512; x += 256) {   // conv1: 4 mt x 2 ks x 64 lanes
        int lane = x & 63, ks = (x >> 6) & 1, mt = x >> 7;
        int o = mt * 16 + (lane & 15);
        int cb = ks * 32 + (lane >> 4) * 8;
        #pragma unroll
        for (int e = 0; e < 8; ++e) {
            ushort2 s = splitbf(w1[o * 64 + cb + e]);
            a1hi[x * 8 + e] = (short)s.x;
            a1lo[x * 8 + e] = (short)s.y;
        }
    }
    for (int x = t; x < 1024; x += 256) {  // conv2: 8 mt x 2 ks x 64 lanes
        int lane = x & 63, ks = (x >> 6) & 1, mt = x >> 7;
        int o = mt * 16 + (lane & 15);
        int cb = ks * 32 + (lane >> 4) * 8;
        #pragma unroll
        for (int e = 0; e < 8; ++e) {
            ushort2 s = splitbf(w2[o * 64 + cb + e]);
            a2hi[x * 8 + e] = (short)s.x;
            a2lo[x * 8 + e] = (short)s.y;
        }
    }
}

// Ball query: one wave per (b,i); first KK ascending indices with d2<=R2, pad with first.
__global__ __launch_bounds__(256) void k_ball(const float* __restrict__ xyz,
                                              int* __restrict__ idx) {
    int wid = blockIdx.x * 4 + (threadIdx.x >> 6);
    int lane = threadIdx.x & 63;
    int b = wid >> 12;
    int i = wid & (NN - 1);
    const float* xb = xyz + b * NN * 3;
    float cx = xb[i * 3 + 0], cy = xb[i * 3 + 1], cz = xb[i * 3 + 2];
    int* out = idx + wid * KK;
    int cnt = 0;
    int firstj = 0;
    for (int base = 0; base < NN; base += 64) {
        int j = base + lane;
        float dx = xb[j * 3 + 0] - cx;
        float dy = xb[j * 3 + 1] - cy;
        float dz = xb[j * 3 + 2] - cz;
        float d2 = __fadd_rn(__fadd_rn(__fmul_rn(dx, dx), __fmul_rn(dy, dy)), __fmul_rn(dz, dz));
        bool valid = d2 <= R2;
        unsigned long long m = __ballot(valid);
        if (cnt == 0 && m != 0ull) firstj = base + (int)__builtin_ctzll(m);
        int pos = (int)__popcll(m & ((1ull << lane) - 1ull));
        if (valid && (cnt + pos) < KK) out[cnt + pos] = j;
        cnt += (int)__popcll(m);
        if (cnt >= KK) break;
    }
    if (cnt < KK) {
        int kpad = cnt + lane;
        if (kpad < KK) out[kpad] = firstj;
    }
}

// Per (b,i,k): 13 fused channels -> f13 (c-major) + GN stats of conv0 output.
__global__ __launch_bounds__(256) void k_feat(
    const float* __restrict__ xyz, const float* __restrict__ feat,
    const int* __restrict__ idx, const float* __restrict__ w0t,
    const float* __restrict__ wap, const float* __restrict__ wbp,
    const float* __restrict__ wcp, float* __restrict__ f13,
    float* __restrict__ stats0) {
    int t = blockIdx.x * 256 + threadIdx.x;
    int b = t / NP, r = t % NP;
    int i = r >> 5;
    int j = idx[t];
    const float* xb = xyz + b * NN * 3;
    const float* fb = feat + b * NN * 3;
    float cx = xb[i * 3], cy = xb[i * 3 + 1], cz = xb[i * 3 + 2];
    float nx = fb[i * 3], ny = fb[i * 3 + 1], nz = fb[i * 3 + 2];
    float gx = xb[j * 3], gy = xb[j * 3 + 1], gz = xb[j * 3 + 2];
    float mx = fb[j * 3], my = fb[j * 3 + 1], mz = fb[j * 3 + 2];
    float dx = gx - cx, dy = gy - cy, dz = gz - cz;
    float d2 = dx * dx + dy * dy + dz * dz;
    float dist = d2 > 0.f ? sqrtf(d2) : 0.f;
    float a1 = angle3(nx, ny, nz, dx, dy, dz);
    float a2 = angle3(mx, my, mz, dx, dy, dz);
    float a3 = angle3(nx, ny, nz, mx, my, mz);
    float WA = wap[0], WB = wbp[0], WC = wcp[0];
    float f[13] = {WA * cx, WA * cy, WA * cz, WA * gx, WA * gy, WA * gz,
                   WB * dx, WB * dy, WB * dz, WB * dist, WC * a1, WC * a2, WC * a3};
    float* fo = f13 + (size_t)b * 13 * NP + r;
    #pragma unroll
    for (int c = 0; c < 13; ++c) fo[(size_t)c * NP] = f[c];
    float acc[64];
    #pragma unroll
    for (int o = 0; o < 64; ++o) acc[o] = 0.f;
    #pragma unroll
    for (int c = 0; c < 13; ++c) {
        float v = f[c];
        const float* wr = w0t + c * 64;
        #pragma unroll
        for (int o = 0; o < 64; ++o) acc[o] = fmaf(wr[o], v, acc[o]);
    }
    float vals[16];
    #pragma unroll
    for (int g = 0; g < 8; ++g) {
        float sv = 0.f, sq = 0.f;
        #pragma unroll
        for (int c2 = 0; c2 < 8; ++c2) { float v = acc[g * 8 + c2]; sv += v; sq = fmaf(v, v, sq); }
        vals[g * 2] = sv; vals[g * 2 + 1] = sq;
    }
    blockReduceAdd<16>(vals, stats0 + b * 16);
}

// conv0(VALU) -> GN0+relu -> split to LDS -> conv1(MFMA split-bf16) -> y1 + stats1
// Block: 128 points. LDS X layout: [p][c] shorts, byte = p*128 + ((c*2) ^ ((p&7)<<4))
__global__ __launch_bounds__(256) void k_conv01m(
    const float* __restrict__ f13, const float* __restrict__ stats0,
    const float* __restrict__ g0, const float* __restrict__ b0,
    const float* __restrict__ w0t,
    const short* __restrict__ a1hi, const short* __restrict__ a1lo,
    float* __restrict__ y1, float* __restrict__ stats1) {
    __shared__ __align__(16) short Xhi[128 * 64];
    __shared__ __align__(16) short Xlo[128 * 64];
    __shared__ float Aff[128];
    int t = threadIdx.x, blk = blockIdx.x;
    int b = blk >> 10;
    int pbase = (blk & 1023) << 7;
    if (t < 64) {
        int c = t, g = c >> 3;
        const float inv = 1.f / 1048576.f;  // (64/8)*K*N
        float s = stats0[b * 16 + g * 2], q = stats0[b * 16 + g * 2 + 1];
        float mean = s * inv;
        float var = q * inv - mean * mean;
        float rstd = rsqrtf(var + GEPS);
        float a = rstd * g0[c];
        Aff[c] = a; Aff[64 + c] = fmaf(-mean, a, b0[c]);
    }
    __syncthreads();
    {   // staging: thread -> (point p, channel-half chalf) : conv0 for 32 channels
        int p = t & 127, chalf = t >> 7;
        const float* fi = f13 + (size_t)b * 13 * NP + pbase + p;
        float fv[13];
        #pragma unroll
        for (int c = 0; c < 13; ++c) fv[c] = fi[(size_t)c * NP];
        float acc[32];
        #pragma unroll
        for (int o = 0; o < 32; ++o) acc[o] = 0.f;
        #pragma unroll
        for (int c = 0; c < 13; ++c) {
            const float* wr = w0t + c * 64 + chalf * 32;
            #pragma unroll
            for (int o = 0; o < 32; ++o) acc[o] = fmaf(wr[o], fv[c], acc[o]);
        }
        int swz = (p & 7) << 4;
        #pragma unroll
        for (int jc = 0; jc < 4; ++jc) {
            int hw[4], lw[4];
            #pragma unroll
            for (int u = 0; u < 4; ++u) {
                int o0 = jc * 8 + u * 2;
                int ch0 = chalf * 32 + o0;
                float v0 = fmaxf(fmaf(Aff[ch0], acc[o0], Aff[64 + ch0]), 0.f);
                float v1 = fmaxf(fmaf(Aff[ch0 + 1], acc[o0 + 1], Aff[64 + ch0 + 1]), 0.f);
                ushort2 s0 = splitbf(v0), s1 = splitbf(v1);
                hw[u] = (int)((unsigned)s0.x | ((unsigned)s1.x << 16));
                lw[u] = (int)((unsigned)s0.y | ((unsigned)s1.y << 16));
            }
            int off = p * 128 + ((chalf * 64 + jc * 16) ^ swz);
            *reinterpret_cast<int4*>((char*)Xhi + off) = make_int4(hw[0], hw[1], hw[2], hw[3]);
            *reinterpret_cast<int4*>((char*)Xlo + off) = make_int4(lw[0], lw[1], lw[2], lw[3]);
        }
    }
    __syncthreads();
    {   // MFMA: wave w owns Mtile w (16 out channels); 8 point-subtiles
        int w = t >> 6, lane = t & 63, col = lane & 15, kb = lane >> 4;
        short8 whi[2], wlo[2];
        #pragma unroll
        for (int ks = 0; ks < 2; ++ks) {
            int fi_ = ((w * 2 + ks) * 64 + lane) * 8;
            whi[ks] = *reinterpret_cast<const short8*>(a1hi + fi_);
            wlo[ks] = *reinterpret_cast<const short8*>(a1lo + fi_);
        }
        float sv = 0.f, sq = 0.f;
        int swzr = (col & 7) << 4;
        float* yb = y1 + (size_t)b * 64 * NP + pbase + col;
        #pragma unroll 2
        for (int s = 0; s < 8; ++s) {
            int rowoff = (s * 16 + col) * 128;
            f32x4 d = {0.f, 0.f, 0.f, 0.f};
            #pragma unroll
            for (int ks = 0; ks < 2; ++ks) {
                int boff = rowoff + ((ks * 64 + kb * 16) ^ swzr);
                short8 bh = *reinterpret_cast<const short8*>((char*)Xhi + boff);
                short8 bl = *reinterpret_cast<const short8*>((char*)Xlo + boff);
                d = __builtin_amdgcn_mfma_f32_16x16x32_bf16(whi[ks], bh, d, 0, 0, 0);
                d = __builtin_amdgcn_mfma_f32_16x16x32_bf16(whi[ks], bl, d, 0, 0, 0);
                d = __builtin_amdgcn_mfma_f32_16x16x32_bf16(wlo[ks], bh, d, 0, 0, 0);
            }
            #pragma unroll
            for (int q = 0; q < 4; ++q) {
                int ch = w * 16 + kb * 4 + q;
                yb[(size_t)ch * NP + s * 16] = d[q];
                sv += d[q];
                sq = fmaf(d[q], d[q], sq);
            }
        }
        #pragma unroll
        for (int m = 1; m <= 16; m <<= 1) {
            sv += __shfl_xor(sv, m, 64);
            sq += __shfl_xor(sq, m, 64);
        }
        if ((lane & 31) == 0) {
            int grp = w * 2 + (lane >> 5);   // GN1 groups are 8 channels = half Mtile
            atomicAdd(&stats1[b * 16 + grp * 2], sv);
            atomicAdd(&stats1[b * 16 + grp * 2 + 1], sq);
        }
    }
}

// GN1+relu+split to LDS -> conv2 (MFMA, M=128) -> stats2 + K-extreme (max/min per gamma2 sign)
__global__ __launch_bounds__(256) void k_conv2m(
    const float* __restrict__ y1, const float* __restrict__ stats1,
    const float* __restrict__ g1, const float* __restrict__ b1,
    const float* __restrict__ g2,
    const short* __restrict__ a2hi, const short* __restrict__ a2lo,
    float* __restrict__ ext, float* __restrict__ stats2) {
    __shared__ __align__(16) short Xhi[128 * 64];
    __shared__ __align__(16) short Xlo[128 * 64];
    __shared__ float Aff[128];
    int t = threadIdx.x, blk = blockIdx.x;
    int b = blk >> 10;
    int pbase = (blk & 1023) << 7;
    if (t < 64) {
        int c = t, g = c >> 3;
        const float inv = 1.f / 1048576.f;
        float s = stats1[b * 16 + g * 2], q = stats1[b * 16 + g * 2 + 1];
        float mean = s * inv;
        float var = q * inv - mean * mean;
        float rstd = rsqrtf(var + GEPS);
        float a = rstd * g1[c];
        Aff[c] = a; Aff[64 + c] = fmaf(-mean, a, b1[c]);
    }
    __syncthreads();
    {   // staging: thread -> (p, 32-channel block)
        int p = t & 127, cblk = t >> 7;
        const float* yi = y1 + (size_t)b * 64 * NP + pbase + p;
        int swz = (p & 7) << 4;
        #pragma unroll
        for (int jc = 0; jc < 4; ++jc) {
            int hw[4], lw[4];
            #pragma unroll
            for (int u = 0; u < 4; ++u) {
                int ch0 = cblk * 32 + jc * 8 + u * 2;
                float v0 = yi[(size_t)ch0 * NP];
                float v1 = yi[(size_t)(ch0 + 1) * NP];
                v0 = fmaxf(fmaf(Aff[ch0], v0, Aff[64 + ch0]), 0.f);
                v1 = fmaxf(fmaf(Aff[ch0 + 1], v1, Aff[64 + ch0 + 1]), 0.f);
                ushort2 s0 = splitbf(v0), s1 = splitbf(v1);
                hw[u] = (int)((unsigned)s0.x | ((unsigned)s1.x << 16));
                lw[u] = (int)((unsigned)s0.y | ((unsigned)s1.y << 16));
            }
            int off = p * 128 + ((cblk * 64 + jc * 16) ^ swz);
            *reinterpret_cast<int4*>((char*)Xhi + off) = make_int4(hw[0], hw[1], hw[2], hw[3]);
            *reinterpret_cast<int4*>((char*)Xlo + off) = make_int4(lw[0], lw[1], lw[2], lw[3]);
        }
    }
    __syncthreads();
    {   // wave w owns Mtiles 2w, 2w+1 (32 of 128 out channels)
        int w = t >> 6, lane = t & 63, col = lane & 15, kb = lane >> 4;
        int mt0 = w * 2;
        short8 whi[2][2], wlo[2][2];
        #pragma unroll
        for (int m = 0; m < 2; ++m)
            #pragma unroll
            for (int ks = 0; ks < 2; ++ks) {
                int fi_ = (((mt0 + m) * 2 + ks) * 64 + lane) * 8;
                whi[m][ks] = *reinterpret_cast<const short8*>(a2hi + fi_);
                wlo[m][ks] = *reinterpret_cast<const short8*>(a2lo + fi_);
            }
        float gv[2][4];
        #pragma unroll
        for (int m = 0; m < 2; ++m)
            #pragma unroll
            for (int q = 0; q < 4; ++q) gv[m][q] = g2[(mt0 + m) * 16 + kb * 4 + q];
        float sv[2] = {0.f, 0.f}, sq[2] = {0.f, 0.f};
        int swzr = (col & 7) << 4;
        int ibase = pbase >> 5;
        #pragma unroll
        for (int sp = 0; sp < 4; ++sp) {   // K-group = 2 subtiles of 16 points
            f32x4 dp0[2], dp1[2];
            #pragma unroll
            for (int ss = 0; ss < 2; ++ss) {
                int rowoff = ((sp * 2 + ss) * 16 + col) * 128;
                short8 bh[2], bl[2];
                #pragma unroll
                for (int ks = 0; ks < 2; ++ks) {
                    int boff = rowoff + ((ks * 64 + kb * 16) ^ swzr);
                    bh[ks] = *reinterpret_cast<const short8*>((char*)Xhi + boff);
                    bl[ks] = *reinterpret_cast<const short8*>((char*)Xlo + boff);
                }
                #pragma unroll
                for (int m = 0; m < 2; ++m) {
                    f32x4 d = {0.f, 0.f, 0.f, 0.f};
                    #pragma unroll
                    for (int ks = 0; ks < 2; ++ks) {
                        d = __builtin_amdgcn_mfma_f32_16x16x32_bf16(whi[m][ks], bh[ks], d, 0, 0, 0);
                        d = __builtin_amdgcn_mfma_f32_16x16x32_bf16(whi[m][ks], bl[ks], d, 0, 0, 0);
                        d = __builtin_amdgcn_mfma_f32_16x16x32_bf16(wlo[m][ks], bh[ks], d, 0, 0, 0);
                    }
                    #pragma unroll
                    for (int q = 0; q < 4; ++q) {
                        sv[m] += d[q];
                        sq[m] = fmaf(d[q], d[q], sq[m]);
                    }
                    if (ss == 0) dp0[m] = d; else dp1[m] = d;
                }
            }
            #pragma unroll
            for (int m = 0; m < 2; ++m) {
                float e[4];
                #pragma unroll
                for (int q = 0; q < 4; ++q) {
                    bool mx = gv[m][q] >= 0.f;
                    e[q] = mx ? fmaxf(dp0[m][q], dp1[m][q]) : fminf(dp0[m][q], dp1[m][q]);
                    #pragma unroll
                    for (int sh = 1; sh <= 8; sh <<= 1) {
                        float o = __shfl_xor(e[q], sh, 64);
                        e[q] = mx ? fmaxf(e[q], o) : fminf(e[q], o);
                    }
                }
                if (col == 0) {
                    #pragma unroll
                    for (int q = 0; q < 4; ++q) {
                        int ch = (mt0 + m) * 16 + kb * 4 + q;
                        ext[((size_t)b * 128 + ch) * NN + ibase + sp] = e[q];
                    }
                }
            }
        }
        #pragma unroll
        for (int m = 0; m < 2; ++m) {
            #pragma unroll
            for (int sh = 1; sh <= 32; sh <<= 1) {
                sv[m] += __shfl_xor(sv[m], sh, 64);
                sq[m] += __shfl_xor(sq[m], sh, 64);
            }
        }
        if (lane == 0) {
            #pragma unroll
            for (int m = 0; m < 2; ++m) {   // GN2 group (16 ch) == Mtile
                atomicAdd(&stats2[b * 16 + (mt0 + m) * 2], sv[m]);
                atomicAdd(&stats2[b * 16 + (mt0 + m) * 2 + 1], sq[m]);
            }
        }
    }
}

__global__ __launch_bounds__(256) void k_final(
    const float* __restrict__ ext, const float* __restrict__ stats2,
    const float* __restrict__ g2, const float* __restrict__ b2,
    float* __restrict__ outp) {
    __shared__ float A[128], Bc[128];
    int t = blockIdx.x * 256 + threadIdx.x;
    int b = t / (128 * NN);
    int rem = t - b * 128 * NN;
    int c = rem >> 12;
    if (threadIdx.x < 128) {
        int cc = threadIdx.x, g = cc >> 4;
        const float inv = 1.f / 2097152.f;
        float s = stats2[b * 16 + g * 2], q = stats2[b * 16 + g * 2 + 1];
        float mean = s * inv;
        float var = q * inv - mean * mean;
        float rstd = rsqrtf(var + GEPS);
        float a = rstd * g2[cc];
        A[cc] = a; Bc[cc] = fmaf(-mean, a, b2[cc]);
    }
    __syncthreads();
    float v = ext[t];
    float val = fmaf(A[c], v, Bc[c]);
    outp[t] = fmaxf(val, 0.f);
    outp[NB * 128 * NN + t] = val;
}

extern "C" void kernel_launch(void* const* d_in, const int* in_sizes, int n_in,
                              void* d_out, int out_size, void* d_ws, size_t ws_size,
                              hipStream_t stream) {
    const float* feat = (const float*)d_in[0];
    const float* xyz  = (const float*)d_in[1];
    const float* w0 = (const float*)d_in[2];
    const float* g0 = (const float*)d_in[3];
    const float* b0 = (const float*)d_in[4];
    const float* w1 = (const float*)d_in[5];
    const float* g1 = (const float*)d_in[6];
    const float* b1 = (const float*)d_in[7];
    const float* w2 = (const float*)d_in[8];
    const float* g2 = (const float*)d_in[9];
    const float* b2 = (const float*)d_in[10];
    const float* wa = (const float*)d_in[11];
    const float* wb = (const float*)d_in[12];
    const float* wc = (const float*)d_in[13];

    char* ws = (char*)d_ws;
    float* stats = (float*)ws;                 // 96 floats
    float* w0t  = (float*)(ws + 4096);
    short* a1hi = (short*)(ws + 16384);        // 8 KB
    short* a1lo = (short*)(ws + 24576);        // 8 KB
    short* a2hi = (short*)(ws + 32768);        // 16 KB
    short* a2lo = (short*)(ws + 49152);        // 16 KB
    int*   idx  = (int*)(ws + 65536);          // 1 MB
    float* f13  = (float*)(ws + (2ull << 20)); // 13.6 MB
    float* y1   = (float*)(ws + (16ull << 20)); // 64 MB
    float* ext  = (float*)(ws + (80ull << 20)); // 4 MB

    hipMemsetAsync(stats, 0, 512, stream);
    hipLaunchKernelGGL(k_prep, dim3(1), dim3(256), 0, stream,
                       w0, w1, w2, w0t, a1hi, a1lo, a2hi, a2lo);
    hipLaunchKernelGGL(k_ball, dim3((NB * NN) / 4), dim3(256), 0, stream, xyz, idx);
    hipLaunchKernelGGL(k_feat, dim3((NB * NP) / 256), dim3(256), 0, stream,
                       xyz, feat, idx, w0t, wa, wb, wc, f13, stats);
    hipLaunchKernelGGL(k_conv01m, dim3((NB * NP) / 128), dim3(256), 0, stream,
                       f13, stats, g0, b0, w0t, a1hi, a1lo, y1, stats + 32);
    hipLaunchKernelGGL(k_conv2m, dim3((NB * NP) / 128), dim3(256), 0, stream,
                       y1, stats + 32, g1, b1, g2, a2hi, a2lo, ext, stats + 64);
    hipLaunchKernelGGL(k_final, dim3((NB * 128 * NN) / 256), dim3(256), 0, stream,
                       ext, stats + 64, g2, b2, (float*)d_out);
}

// Round 6
// 214.886 us; speedup vs baseline: 2.9793x; 2.9793x over previous
//
#include <hip/hip_runtime.h>
#include <hip/hip_bf16.h>

#define DEVINL __device__ __forceinline__

typedef short short8 __attribute__((ext_vector_type(8)));
typedef float f32x4 __attribute__((ext_vector_type(4)));

namespace {
constexpr int NB = 2;
constexpr int NN = 4096;
constexpr int KK = 32;
constexpr int NP = NN * KK;      // 131072 points per batch
constexpr float R2 = 0.01f;
constexpr float GEPS = 1e-5f;
}

// split fp32 v into bf16 hi + bf16 lo (truncation; v - hi is exact)
DEVINL ushort2 splitbf(float v) {
    unsigned int b = __float_as_uint(v);
    unsigned int hb = b & 0xffff0000u;
    float r = v - __uint_as_float(hb);
    unsigned int lb = __float_as_uint(r);
    ushort2 res;
    res.x = (unsigned short)(hb >> 16);
    res.y = (unsigned short)(lb >> 16);
    return res;
}

DEVINL float angle3(float ax, float ay, float az, float bx, float by, float bz) {
    float crx = ay * bz - az * by;
    float cry = az * bx - ax * bz;
    float crz = ax * by - ay * bx;
    float sq = crx * crx + cry * cry + crz * crz;
    float yv = sq > 0.f ? sqrtf(sq) : 0.f;
    float xv = ax * bx + ay * by + az * bz;
    if (yv == 0.f && xv == 0.f) return 0.f;
    return atan2f(yv, xv);
}

// Reduce NV per-thread partials across the block; thread q<NV gets sum q. No atomics.
template <int NV>
DEVINL float blockReducePart(float* vals) {
    #pragma unroll
    for (int m = 1; m < 64; m <<= 1) {
        #pragma unroll
        for (int q = 0; q < NV; ++q) vals[q] += __shfl_xor(vals[q], m, 64);
    }
    __shared__ float red[4][NV];
    int lane = threadIdx.x & 63, w = threadIdx.x >> 6;
    if (lane == 0) {
        #pragma unroll
        for (int q = 0; q < NV; ++q) red[w][q] = vals[q];
    }
    __syncthreads();
    float v = 0.f;
    if ((int)threadIdx.x < NV)
        v = red[0][threadIdx.x] + red[1][threadIdx.x] +
            red[2][threadIdx.x] + red[3][threadIdx.x];
    return v;
}

// Sum per-block partials: part[o*nblk .. o*nblk+nblk) -> stats[o]. Grid = 32 blocks.
__global__ __launch_bounds__(256) void k_red(const float* __restrict__ part,
                                             float* __restrict__ stats, int nblk) {
    int o = blockIdx.x;
    const float* p = part + (size_t)o * nblk;
    float s = 0.f;
    for (int i = threadIdx.x; i < nblk; i += 256) s += p[i];
    #pragma unroll
    for (int m = 1; m < 64; m <<= 1) s += __shfl_xor(s, m, 64);
    __shared__ float r[4];
    if ((threadIdx.x & 63) == 0) r[threadIdx.x >> 6] = s;
    __syncthreads();
    if (threadIdx.x == 0) stats[o] = r[0] + r[1] + r[2] + r[3];
}

// w0t[c*64+o] = w0[o*13+c]; a1/a2: split-bf16 weights in MFMA A-frag layout.
// A-frag entry x = mt*128 + ks*64 + lane; element e: W[mt*16+(lane&15)][ks*32+(lane>>4)*8+e]
__global__ void k_prep(const float* __restrict__ w0, const float* __restrict__ w1,
                       const float* __restrict__ w2, float* __restrict__ w0t,
                       short* __restrict__ a1hi, short* __restrict__ a1lo,
                       short* __restrict__ a2hi, short* __restrict__ a2lo) {
    int t = threadIdx.x;
    for (int x = t; x < 64 * 13; x += 256) { int o = x / 13, c = x % 13; w0t[c * 64 + o] = w0[x]; }
    for (int x = t; x < 512; x += 256) {   // conv1: 4 mt x 2 ks x 64 lanes
        int lane = x & 63, ks = (x >> 6) & 1, mt = x >> 7;
        int o = mt * 16 + (lane & 15);
        int cb = ks * 32 + (lane >> 4) * 8;
        #pragma unroll
        for (int e = 0; e < 8; ++e) {
            ushort2 s = splitbf(w1[o * 64 + cb + e]);
            a1hi[x * 8 + e] = (short)s.x;
            a1lo[x * 8 + e] = (short)s.y;
        }
    }
    for (int x = t; x < 1024; x += 256) {  // conv2: 8 mt x 2 ks x 64 lanes
        int lane = x & 63, ks = (x >> 6) & 1, mt = x >> 7;
        int o = mt * 16 + (lane & 15);
        int cb = ks * 32 + (lane >> 4) * 8;
        #pragma unroll
        for (int e = 0; e < 8; ++e) {
            ushort2 s = splitbf(w2[o * 64 + cb + e]);
            a2hi[x * 8 + e] = (short)s.x;
            a2lo[x * 8 + e] = (short)s.y;
        }
    }
}

// Ball query: one wave per (b,i); first KK ascending indices with d2<=R2, pad with first.
__global__ __launch_bounds__(256) void k_ball(const float* __restrict__ xyz,
                                              int* __restrict__ idx) {
    int wid = blockIdx.x * 4 + (threadIdx.x >> 6);
    int lane = threadIdx.x & 63;
    int b = wid >> 12;
    int i = wid & (NN - 1);
    const float* xb = xyz + b * NN * 3;
    float cx = xb[i * 3 + 0], cy = xb[i * 3 + 1], cz = xb[i * 3 + 2];
    int* out = idx + wid * KK;
    int cnt = 0;
    int firstj = 0;
    for (int base = 0; base < NN; base += 64) {
        int j = base + lane;
        float dx = xb[j * 3 + 0] - cx;
        float dy = xb[j * 3 + 1] - cy;
        float dz = xb[j * 3 + 2] - cz;
        float d2 = __fadd_rn(__fadd_rn(__fmul_rn(dx, dx), __fmul_rn(dy, dy)), __fmul_rn(dz, dz));
        bool valid = d2 <= R2;
        unsigned long long m = __ballot(valid);
        if (cnt == 0 && m != 0ull) firstj = base + (int)__builtin_ctzll(m);
        int pos = (int)__popcll(m & ((1ull << lane) - 1ull));
        if (valid && (cnt + pos) < KK) out[cnt + pos] = j;
        cnt += (int)__popcll(m);
        if (cnt >= KK) break;
    }
    if (cnt < KK) {
        int kpad = cnt + lane;
        if (kpad < KK) out[kpad] = firstj;
    }
}

// Per (b,i,k): 13 fused channels -> f13 (c-major) + per-block partial GN0 stats.
__global__ __launch_bounds__(256) void k_feat(
    const float* __restrict__ xyz, const float* __restrict__ feat,
    const int* __restrict__ idx, const float* __restrict__ w0t,
    const float* __restrict__ wap, const float* __restrict__ wbp,
    const float* __restrict__ wcp, float* __restrict__ f13,
    float* __restrict__ part0) {
    int t = blockIdx.x * 256 + threadIdx.x;
    int b = t / NP, r = t % NP;
    int i = r >> 5;
    int j = idx[t];
    const float* xb = xyz + b * NN * 3;
    const float* fb = feat + b * NN * 3;
    float cx = xb[i * 3], cy = xb[i * 3 + 1], cz = xb[i * 3 + 2];
    float nx = fb[i * 3], ny = fb[i * 3 + 1], nz = fb[i * 3 + 2];
    float gx = xb[j * 3], gy = xb[j * 3 + 1], gz = xb[j * 3 + 2];
    float mx = fb[j * 3], my = fb[j * 3 + 1], mz = fb[j * 3 + 2];
    float dx = gx - cx, dy = gy - cy, dz = gz - cz;
    float d2 = dx * dx + dy * dy + dz * dz;
    float dist = d2 > 0.f ? sqrtf(d2) : 0.f;
    float a1 = angle3(nx, ny, nz, dx, dy, dz);
    float a2 = angle3(mx, my, mz, dx, dy, dz);
    float a3 = angle3(nx, ny, nz, mx, my, mz);
    float WA = wap[0], WB = wbp[0], WC = wcp[0];
    float f[13] = {WA * cx, WA * cy, WA * cz, WA * gx, WA * gy, WA * gz,
                   WB * dx, WB * dy, WB * dz, WB * dist, WC * a1, WC * a2, WC * a3};
    float* fo = f13 + (size_t)b * 13 * NP + r;
    #pragma unroll
    for (int c = 0; c < 13; ++c) fo[(size_t)c * NP] = f[c];
    float acc[64];
    #pragma unroll
    for (int o = 0; o < 64; ++o) acc[o] = 0.f;
    #pragma unroll
    for (int c = 0; c < 13; ++c) {
        float v = f[c];
        const float* wr = w0t + c * 64;
        #pragma unroll
        for (int o = 0; o < 64; ++o) acc[o] = fmaf(wr[o], v, acc[o]);
    }
    float vals[16];
    #pragma unroll
    for (int g = 0; g < 8; ++g) {
        float sv = 0.f, sq = 0.f;
        #pragma unroll
        for (int c2 = 0; c2 < 8; ++c2) { float v = acc[g * 8 + c2]; sv += v; sq = fmaf(v, v, sq); }
        vals[g * 2] = sv; vals[g * 2 + 1] = sq;
    }
    float pv = blockReducePart<16>(vals);
    if ((int)threadIdx.x < 16) {
        int blkInB = blockIdx.x & 511;   // 512 blocks per batch
        part0[(size_t)(b * 16 + threadIdx.x) * 512 + blkInB] = pv;
    }
}

// conv0(VALU) -> GN0+relu -> split to LDS -> conv1(MFMA split-bf16) -> y1 + partial stats1
// Block: 128 points. LDS X layout: [p][c] shorts, byte = p*128 + ((c*2) ^ ((p&7)<<4))
__global__ __launch_bounds__(256) void k_conv01m(
    const float* __restrict__ f13, const float* __restrict__ stats0,
    const float* __restrict__ g0, const float* __restrict__ b0,
    const float* __restrict__ w0t,
    const short* __restrict__ a1hi, const short* __restrict__ a1lo,
    float* __restrict__ y1, float* __restrict__ part1) {
    __shared__ __align__(16) short Xhi[128 * 64];
    __shared__ __align__(16) short Xlo[128 * 64];
    __shared__ float Aff[128];
    int t = threadIdx.x, blk = blockIdx.x;
    int b = blk >> 10;
    int blkInB = blk & 1023;
    int pbase = blkInB << 7;
    if (t < 64) {
        int c = t, g = c >> 3;
        const float inv = 1.f / 1048576.f;  // (64/8)*K*N
        float s = stats0[b * 16 + g * 2], q = stats0[b * 16 + g * 2 + 1];
        float mean = s * inv;
        float var = q * inv - mean * mean;
        float rstd = rsqrtf(var + GEPS);
        float a = rstd * g0[c];
        Aff[c] = a; Aff[64 + c] = fmaf(-mean, a, b0[c]);
    }
    __syncthreads();
    {   // staging: thread -> (point p, channel-half chalf) : conv0 for 32 channels
        int p = t & 127, chalf = t >> 7;
        const float* fi = f13 + (size_t)b * 13 * NP + pbase + p;
        float fv[13];
        #pragma unroll
        for (int c = 0; c < 13; ++c) fv[c] = fi[(size_t)c * NP];
        float acc[32];
        #pragma unroll
        for (int o = 0; o < 32; ++o) acc[o] = 0.f;
        #pragma unroll
        for (int c = 0; c < 13; ++c) {
            const float* wr = w0t + c * 64 + chalf * 32;
            #pragma unroll
            for (int o = 0; o < 32; ++o) acc[o] = fmaf(wr[o], fv[c], acc[o]);
        }
        int swz = (p & 7) << 4;
        #pragma unroll
        for (int jc = 0; jc < 4; ++jc) {
            int hw[4], lw[4];
            #pragma unroll
            for (int u = 0; u < 4; ++u) {
                int o0 = jc * 8 + u * 2;
                int ch0 = chalf * 32 + o0;
                float v0 = fmaxf(fmaf(Aff[ch0], acc[o0], Aff[64 + ch0]), 0.f);
                float v1 = fmaxf(fmaf(Aff[ch0 + 1], acc[o0 + 1], Aff[64 + ch0 + 1]), 0.f);
                ushort2 s0 = splitbf(v0), s1 = splitbf(v1);
                hw[u] = (int)((unsigned)s0.x | ((unsigned)s1.x << 16));
                lw[u] = (int)((unsigned)s0.y | ((unsigned)s1.y << 16));
            }
            int off = p * 128 + ((chalf * 64 + jc * 16) ^ swz);
            *reinterpret_cast<int4*>((char*)Xhi + off) = make_int4(hw[0], hw[1], hw[2], hw[3]);
            *reinterpret_cast<int4*>((char*)Xlo + off) = make_int4(lw[0], lw[1], lw[2], lw[3]);
        }
    }
    __syncthreads();
    {   // MFMA: wave w owns Mtile w (16 out channels); 8 point-subtiles
        int w = t >> 6, lane = t & 63, col = lane & 15, kb = lane >> 4;
        short8 whi[2], wlo[2];
        #pragma unroll
        for (int ks = 0; ks < 2; ++ks) {
            int fi_ = ((w * 2 + ks) * 64 + lane) * 8;
            whi[ks] = *reinterpret_cast<const short8*>(a1hi + fi_);
            wlo[ks] = *reinterpret_cast<const short8*>(a1lo + fi_);
        }
        float sv = 0.f, sq = 0.f;
        int swzr = (col & 7) << 4;
        float* yb = y1 + (size_t)b * 64 * NP + pbase + col;
        #pragma unroll 2
        for (int s = 0; s < 8; ++s) {
            int rowoff = (s * 16 + col) * 128;
            f32x4 d = {0.f, 0.f, 0.f, 0.f};
            #pragma unroll
            for (int ks = 0; ks < 2; ++ks) {
                int boff = rowoff + ((ks * 64 + kb * 16) ^ swzr);
                short8 bh = *reinterpret_cast<const short8*>((char*)Xhi + boff);
                short8 bl = *reinterpret_cast<const short8*>((char*)Xlo + boff);
                d = __builtin_amdgcn_mfma_f32_16x16x32_bf16(whi[ks], bh, d, 0, 0, 0);
                d = __builtin_amdgcn_mfma_f32_16x16x32_bf16(whi[ks], bl, d, 0, 0, 0);
                d = __builtin_amdgcn_mfma_f32_16x16x32_bf16(wlo[ks], bh, d, 0, 0, 0);
            }
            #pragma unroll
            for (int q = 0; q < 4; ++q) {
                int ch = w * 16 + kb * 4 + q;
                yb[(size_t)ch * NP + s * 16] = d[q];
                sv += d[q];
                sq = fmaf(d[q], d[q], sq);
            }
        }
        #pragma unroll
        for (int m = 1; m <= 16; m <<= 1) {
            sv += __shfl_xor(sv, m, 64);
            sq += __shfl_xor(sq, m, 64);
        }
        if ((lane & 31) == 0) {
            int grp = w * 2 + (lane >> 5);   // GN1 groups are 8 channels = half Mtile
            size_t o = (size_t)(b * 16 + grp * 2) * 1024 + blkInB;
            part1[o] = sv;
            part1[o + 1024] = sq;
        }
    }
}

// GN1+relu+split to LDS -> conv2 (MFMA, M=128) -> partial stats2 + K-extreme
__global__ __launch_bounds__(256) void k_conv2m(
    const float* __restrict__ y1, const float* __restrict__ stats1,
    const float* __restrict__ g1, const float* __restrict__ b1,
    const float* __restrict__ g2,
    const short* __restrict__ a2hi, const short* __restrict__ a2lo,
    float* __restrict__ ext, float* __restrict__ part2) {
    __shared__ __align__(16) short Xhi[128 * 64];
    __shared__ __align__(16) short Xlo[128 * 64];
    __shared__ float Aff[128];
    int t = threadIdx.x, blk = blockIdx.x;
    int b = blk >> 10;
    int blkInB = blk & 1023;
    int pbase = blkInB << 7;
    if (t < 64) {
        int c = t, g = c >> 3;
        const float inv = 1.f / 1048576.f;
        float s = stats1[b * 16 + g * 2], q = stats1[b * 16 + g * 2 + 1];
        float mean = s * inv;
        float var = q * inv - mean * mean;
        float rstd = rsqrtf(var + GEPS);
        float a = rstd * g1[c];
        Aff[c] = a; Aff[64 + c] = fmaf(-mean, a, b1[c]);
    }
    __syncthreads();
    {   // staging: thread -> (p, 32-channel block)
        int p = t & 127, cblk = t >> 7;
        const float* yi = y1 + (size_t)b * 64 * NP + pbase + p;
        int swz = (p & 7) << 4;
        #pragma unroll
        for (int jc = 0; jc < 4; ++jc) {
            int hw[4], lw[4];
            #pragma unroll
            for (int u = 0; u < 4; ++u) {
                int ch0 = cblk * 32 + jc * 8 + u * 2;
                float v0 = yi[(size_t)ch0 * NP];
                float v1 = yi[(size_t)(ch0 + 1) * NP];
                v0 = fmaxf(fmaf(Aff[ch0], v0, Aff[64 + ch0]), 0.f);
                v1 = fmaxf(fmaf(Aff[ch0 + 1], v1, Aff[64 + ch0 + 1]), 0.f);
                ushort2 s0 = splitbf(v0), s1 = splitbf(v1);
                hw[u] = (int)((unsigned)s0.x | ((unsigned)s1.x << 16));
                lw[u] = (int)((unsigned)s0.y | ((unsigned)s1.y << 16));
            }
            int off = p * 128 + ((cblk * 64 + jc * 16) ^ swz);
            *reinterpret_cast<int4*>((char*)Xhi + off) = make_int4(hw[0], hw[1], hw[2], hw[3]);
            *reinterpret_cast<int4*>((char*)Xlo + off) = make_int4(lw[0], lw[1], lw[2], lw[3]);
        }
    }
    __syncthreads();
    {   // wave w owns Mtiles 2w, 2w+1 (32 of 128 out channels)
        int w = t >> 6, lane = t & 63, col = lane & 15, kb = lane >> 4;
        int mt0 = w * 2;
        short8 whi[2][2], wlo[2][2];
        #pragma unroll
        for (int m = 0; m < 2; ++m)
            #pragma unroll
            for (int ks = 0; ks < 2; ++ks) {
                int fi_ = (((mt0 + m) * 2 + ks) * 64 + lane) * 8;
                whi[m][ks] = *reinterpret_cast<const short8*>(a2hi + fi_);
                wlo[m][ks] = *reinterpret_cast<const short8*>(a2lo + fi_);
            }
        float gv[2][4];
        #pragma unroll
        for (int m = 0; m < 2; ++m)
            #pragma unroll
            for (int q = 0; q < 4; ++q) gv[m][q] = g2[(mt0 + m) * 16 + kb * 4 + q];
        float sv[2] = {0.f, 0.f}, sq[2] = {0.f, 0.f};
        int swzr = (col & 7) << 4;
        int ibase = pbase >> 5;
        #pragma unroll
        for (int sp = 0; sp < 4; ++sp) {   // K-group = 2 subtiles of 16 points
            f32x4 dp0[2], dp1[2];
            #pragma unroll
            for (int ss = 0; ss < 2; ++ss) {
                int rowoff = ((sp * 2 + ss) * 16 + col) * 128;
                short8 bh[2], bl[2];
                #pragma unroll
                for (int ks = 0; ks < 2; ++ks) {
                    int boff = rowoff + ((ks * 64 + kb * 16) ^ swzr);
                    bh[ks] = *reinterpret_cast<const short8*>((char*)Xhi + boff);
                    bl[ks] = *reinterpret_cast<const short8*>((char*)Xlo + boff);
                }
                #pragma unroll
                for (int m = 0; m < 2; ++m) {
                    f32x4 d = {0.f, 0.f, 0.f, 0.f};
                    #pragma unroll
                    for (int ks = 0; ks < 2; ++ks) {
                        d = __builtin_amdgcn_mfma_f32_16x16x32_bf16(whi[m][ks], bh[ks], d, 0, 0, 0);
                        d = __builtin_amdgcn_mfma_f32_16x16x32_bf16(whi[m][ks], bl[ks], d, 0, 0, 0);
                        d = __builtin_amdgcn_mfma_f32_16x16x32_bf16(wlo[m][ks], bh[ks], d, 0, 0, 0);
                    }
                    #pragma unroll
                    for (int q = 0; q < 4; ++q) {
                        sv[m] += d[q];
                        sq[m] = fmaf(d[q], d[q], sq[m]);
                    }
                    if (ss == 0) dp0[m] = d; else dp1[m] = d;
                }
            }
            #pragma unroll
            for (int m = 0; m < 2; ++m) {
                float e[4];
                #pragma unroll
                for (int q = 0; q < 4; ++q) {
                    bool mx = gv[m][q] >= 0.f;
                    e[q] = mx ? fmaxf(dp0[m][q], dp1[m][q]) : fminf(dp0[m][q], dp1[m][q]);
                    #pragma unroll
                    for (int sh = 1; sh <= 8; sh <<= 1) {
                        float o = __shfl_xor(e[q], sh, 64);
                        e[q] = mx ? fmaxf(e[q], o) : fminf(e[q], o);
                    }
                }
                if (col == 0) {
                    #pragma unroll
                    for (int q = 0; q < 4; ++q) {
                        int ch = (mt0 + m) * 16 + kb * 4 + q;
                        ext[((size_t)b * 128 + ch) * NN + ibase + sp] = e[q];
                    }
                }
            }
        }
        #pragma unroll
        for (int m = 0; m < 2; ++m) {
            #pragma unroll
            for (int sh = 1; sh <= 32; sh <<= 1) {
                sv[m] += __shfl_xor(sv[m], sh, 64);
                sq[m] += __shfl_xor(sq[m], sh, 64);
            }
        }
        if (lane == 0) {
            #pragma unroll
            for (int m = 0; m < 2; ++m) {   // GN2 group (16 ch) == Mtile
                size_t o = (size_t)(b * 16 + (mt0 + m) * 2) * 1024 + blkInB;
                part2[o] = sv[m];
                part2[o + 1024] = sq[m];
            }
        }
    }
}

__global__ __launch_bounds__(256) void k_final(
    const float* __restrict__ ext, const float* __restrict__ stats2,
    const float* __restrict__ g2, const float* __restrict__ b2,
    float* __restrict__ outp) {
    __shared__ float A[128], Bc[128];
    int t = blockIdx.x * 256 + threadIdx.x;
    int b = t / (128 * NN);
    int rem = t - b * 128 * NN;
    int c = rem >> 12;
    if (threadIdx.x < 128) {
        int cc = threadIdx.x, g = cc >> 4;
        const float inv = 1.f / 2097152.f;
        float s = stats2[b * 16 + g * 2], q = stats2[b * 16 + g * 2 + 1];
        float mean = s * inv;
        float var = q * inv - mean * mean;
        float rstd = rsqrtf(var + GEPS);
        float a = rstd * g2[cc];
        A[cc] = a; Bc[cc] = fmaf(-mean, a, b2[cc]);
    }
    __syncthreads();
    float v = ext[t];
    float val = fmaf(A[c], v, Bc[c]);
    outp[t] = fmaxf(val, 0.f);
    outp[NB * 128 * NN + t] = val;
}

extern "C" void kernel_launch(void* const* d_in, const int* in_sizes, int n_in,
                              void* d_out, int out_size, void* d_ws, size_t ws_size,
                              hipStream_t stream) {
    const float* feat = (const float*)d_in[0];
    const float* xyz  = (const float*)d_in[1];
    const float* w0 = (const float*)d_in[2];
    const float* g0 = (const float*)d_in[3];
    const float* b0 = (const float*)d_in[4];
    const float* w1 = (const float*)d_in[5];
    const float* g1 = (const float*)d_in[6];
    const float* b1 = (const float*)d_in[7];
    const float* w2 = (const float*)d_in[8];
    const float* g2 = (const float*)d_in[9];
    const float* b2 = (const float*)d_in[10];
    const float* wa = (const float*)d_in[11];
    const float* wb = (const float*)d_in[12];
    const float* wc = (const float*)d_in[13];

    char* ws = (char*)d_ws;
    float* stats = (float*)ws;                  // 96 floats (3 x B x 8grp x {s,ss})
    float* w0t  = (float*)(ws + 4096);
    short* a1hi = (short*)(ws + 16384);         // 8 KB
    short* a1lo = (short*)(ws + 24576);         // 8 KB
    short* a2hi = (short*)(ws + 32768);         // 16 KB
    short* a2lo = (short*)(ws + 49152);         // 16 KB
    int*   idx  = (int*)(ws + 65536);           // 1 MB  [64K, 1.0625M)
    float* part0 = (float*)(ws + 1179648);      // 32*512 floats  (64 KB)
    float* part1 = (float*)(ws + 1245184);      // 32*1024 floats (128 KB)
    float* part2 = (float*)(ws + 1376256);      // 32*1024 floats (128 KB)
    float* f13  = (float*)(ws + (2ull << 20));  // 13.6 MB
    float* y1   = (float*)(ws + (16ull << 20)); // 64 MB
    float* ext  = (float*)(ws + (80ull << 20)); // 4 MB

    hipLaunchKernelGGL(k_prep, dim3(1), dim3(256), 0, stream,
                       w0, w1, w2, w0t, a1hi, a1lo, a2hi, a2lo);
    hipLaunchKernelGGL(k_ball, dim3((NB * NN) / 4), dim3(256), 0, stream, xyz, idx);
    hipLaunchKernelGGL(k_feat, dim3((NB * NP) / 256), dim3(256), 0, stream,
                       xyz, feat, idx, w0t, wa, wb, wc, f13, part0);
    hipLaunchKernelGGL(k_red, dim3(32), dim3(256), 0, stream, part0, stats, 512);
    hipLaunchKernelGGL(k_conv01m, dim3((NB * NP) / 128), dim3(256), 0, stream,
                       f13, stats, g0, b0, w0t, a1hi, a1lo, y1, part1);
    hipLaunchKernelGGL(k_red, dim3(32), dim3(256), 0, stream, part1, stats + 32, 1024);
    hipLaunchKernelGGL(k_conv2m, dim3((NB * NP) / 128), dim3(256), 0, stream,
                       y1, stats + 32, g1, b1, g2, a2hi, a2lo, ext, part2);
    hipLaunchKernelGGL(k_red, dim3(32), dim3(256), 0, stream, part2, stats + 64, 1024);
    hipLaunchKernelGGL(k_final, dim3((NB * 128 * NN) / 256), dim3(256), 0, stream,
                       ext, stats + 64, g2, b2, (float*)d_out);
}